// Round 13
// baseline (196.445 us; speedup 1.0000x reference)
//
#include <hip/hip_runtime.h>
#include <hip/hip_cooperative_groups.h>
#include <math.h>

namespace cg = cooperative_groups;

#define BD 8
#define SD 1024
#define ID 64
#define OD 128
#define NBD 6
#define TI 8            // i-tile per nk unit
#define SCH 32          // s-chunk per block (Chebyshev re-init interval)
#define SS 8            // s per super-step (one MFMA wave each)
#define WPAD 136        // padded LDS row (bf16 elems): 272B rows -> conflict-free

typedef short bf16x8 __attribute__((ext_vector_type(8)));
typedef float f32x4 __attribute__((ext_vector_type(4)));

__device__ __forceinline__ ushort rne_bf16(float f) {
    union { float f; unsigned u; } cv; cv.f = f;
    return (ushort)((cv.u + 0x7FFFu + ((cv.u >> 16) & 1u)) >> 16);
}

// One cooperative kernel: phase0 prep -> sync -> phase1 ln -> sync -> phase2 nk
__global__ __launch_bounds__(512) void fused_all(
    const float* __restrict__ seq,    // (8,1024,64)
    const float* __restrict__ M,      // (128,64)
    const float* __restrict__ P,      // (128,128,6)
    const float* __restrict__ resW,   // (128,64)
    const float* __restrict__ gamma,
    const float* __restrict__ beta,
    float* __restrict__ P4,           // ws: [i][g][j]
    float* __restrict__ MT,           // ws: [j][i]
    float* __restrict__ RT,           // ws: [j][i]
    ushort* __restrict__ xnT,         // ws: (1024,8,128) bf16 [s][b][j]
    float* __restrict__ out)          // (8,1024,128)
{
    cg::grid_group gridg = cg::this_grid();
    const int t   = threadIdx.x;
    const int bid = blockIdx.x;

    __shared__ ushort Wl[SS][TI][WPAD];    // 17.4 KB
    __shared__ ushort Xl[SS][16][WPAD];    // 34.8 KB (A rows 8..15 unused)
    __shared__ float  Cst[SS][BD][TI];     // 2 KB epilogue stage
    __shared__ float  red[2][2][16];

    // ================= phase 0: prep (grid-strided, one elem/thread) ========
    {
        const int idx = bid * 512 + t;
        const int NP = OD * OD * NBD;      // 98304
        if (idx < NP) {
            const int j = idx & 127;
            const int r = idx >> 7;        // i*6+g
            const int g = r % NBD;
            const int i = r / NBD;
            P4[idx] = P[(i * OD + j) * NBD + g];
        } else if (idx < NP + OD * ID) {
            const int k = idx - NP;
            const int i = k / ID, j = k - i * ID;
            MT[j * OD + i] = M[k];
        } else if (idx < NP + 2 * OD * ID) {
            const int k = idx - NP - OD * ID;
            const int i = k / ID, j = k - i * ID;
            RT[j * OD + i] = resW[k];
        }
    }
    __threadfence();
    gridg.sync();

    // ================= phase 1: proj + LN for 4 s ===========================
    {
        const int i    = t & 127;
        const int mat  = (t >> 7) & 1;     // wave-uniform
        const int half = t >> 8;           // wave-uniform

        float w[ID];
        {
            const float* __restrict__ WT = (mat ? RT : MT) + i;
            #pragma unroll
            for (int j = 0; j < ID; ++j) w[j] = WT[j * OD];   // coalesced
        }
        const float gm = gamma[i];
        const float bt = beta[i];

        for (int sl = 0; sl < 2; ++sl) {
            const int s = bid * 4 + sl * 2 + half;

            float acc[BD];
            #pragma unroll
            for (int b = 0; b < BD; ++b) {
                const float* __restrict__ xp = &seq[(b * SD + s) * ID]; // s_load
                float a0 = 0.f, a1 = 0.f;
                #pragma unroll
                for (int j = 0; j < ID; j += 2) {
                    a0 = fmaf(xp[j],     w[j],     a0);
                    a1 = fmaf(xp[j + 1], w[j + 1], a1);
                }
                acc[b] = a0 + a1;
            }

            if (mat == 0) {
                float sum[BD], ssq[BD];
                #pragma unroll
                for (int b = 0; b < BD; ++b) { sum[b] = acc[b]; ssq[b] = acc[b] * acc[b]; }
                #pragma unroll
                for (int m = 1; m < 64; m <<= 1) {
                    #pragma unroll
                    for (int b = 0; b < BD; ++b) {
                        sum[b] += __shfl_xor(sum[b], m, 64);
                        ssq[b] += __shfl_xor(ssq[b], m, 64);
                    }
                }
                if ((t & 63) == 0) {
                    const int wv2 = (t >> 6) & 1;
                    #pragma unroll
                    for (int b = 0; b < BD; ++b) {
                        red[half][wv2][b]     = sum[b];
                        red[half][wv2][8 + b] = ssq[b];
                    }
                }
            }
            __syncthreads();

            if (mat == 0) {
                #pragma unroll
                for (int b = 0; b < BD; ++b) {
                    const float sm = red[half][0][b] + red[half][1][b];
                    const float sq = red[half][0][8 + b] + red[half][1][8 + b];
                    const float mu = sm * (1.0f / OD);
                    const float vr = sq * (1.0f / OD) - mu * mu;
                    const float rstd = rsqrtf(vr + 1e-5f);
                    const float xv = (acc[b] - mu) * rstd * gm + bt;
                    xnT[(s * BD + b) * OD + i] = rne_bf16(xv);
                }
            } else {
                #pragma unroll
                for (int b = 0; b < BD; ++b)
                    out[(b * SD + s) * OD + i] = acc[b];   // residual
            }
            __syncthreads();   // protect red[] for next sl
        }
    }
    __threadfence();
    gridg.sync();

    // ================= phase 2: Chebyshev W-gen + MFMA + coalesced RMW ======
    {
        const int sc  = bid & 31;          // s-chunk
        const int ith = bid >> 5;          // 0..7 -> two TI=8 units
        const int il  = t >> 6;            // wave id / local i (phase1 role)
        const int jb  = t & 63;
        const int l   = t & 63;

        for (int u2 = 0; u2 < 2; ++u2) {
            const int it = ith * 2 + u2;
            const int i0 = it * TI;
            const int ig = i0 + il;

            // init 12 Chebyshev states
            float Pv[12], kk[12], c0[12], c1[12];
            const float s0f = (float)(sc * SCH);
            #pragma unroll
            for (int p = 0; p < 2; ++p) {
                const int j = jb + p * 64;
                #pragma unroll
                for (int g = 0; g < NBD; ++g) {
                    const int q = p * NBD + g;
                    Pv[q] = P4[(ig * NBD + g) * OD + j];                // coalesced
                    const float per = (float)(ig * (OD * NBD) + j * NBD + g + 2);
                    const float rp  = __builtin_amdgcn_rcpf(per);       // rev/step
                    kk[q] = 2.0f * __builtin_amdgcn_cosf(rp);
                    c1[q] = __builtin_amdgcn_cosf(__builtin_amdgcn_fractf(s0f * rp));
                    c0[q] = __builtin_amdgcn_cosf(__builtin_amdgcn_fractf((s0f - 1.0f) * rp));
                }
            }

            for (int u = 0; u < SCH / SS; ++u) {
                const int sb = sc * SCH + u * SS;
                // stage xn tile 8s x 8b x 128j bf16 = 16 KB (coalesced uint4)
                {
                    const uint4* __restrict__ src = (const uint4*)(xnT + sb * (BD * OD));
                    #pragma unroll
                    for (int r = 0; r < 2; ++r) {
                        const int e  = t + 512 * r;
                        const uint4 v = src[e];
                        const int eo = e << 3;
                        const int si = eo >> 10;
                        const int b  = (eo >> 7) & 7;
                        const int j0 = eo & 127;
                        *(uint4*)&Xl[si][b][j0] = v;
                    }
                }
                // W-gen: 2 FMA per element
                #pragma unroll
                for (int ssi = 0; ssi < SS; ++ssi) {
                    #pragma unroll
                    for (int p = 0; p < 2; ++p) {
                        float wv = 0.f;
                        #pragma unroll
                        for (int g = 0; g < NBD; ++g)
                            wv = fmaf(Pv[p * NBD + g], c1[p * NBD + g], wv);
                        #pragma unroll
                        for (int g = 0; g < NBD; ++g) {
                            const int q = p * NBD + g;
                            const float cn = fmaf(kk[q], c1[q], -c0[q]);  // Chebyshev
                            c0[q] = c1[q]; c1[q] = cn;
                        }
                        Wl[ssi][il][jb + p * 64] = rne_bf16(wv);
                    }
                }
                __syncthreads();
                // MFMA: wave il handles s = sb + il
                {
                    f32x4 acc4 = {0.f, 0.f, 0.f, 0.f};
                    #pragma unroll
                    for (int m = 0; m < 4; ++m) {
                        const bf16x8 a = *(const bf16x8*)&Xl[il][l & 15][m * 32 + (l >> 4) * 8];
                        const bf16x8 b = *(const bf16x8*)&Wl[il][l & 7][m * 32 + (l >> 4) * 8];
                        acc4 = __builtin_amdgcn_mfma_f32_16x16x32_bf16(a, b, acc4, 0, 0, 0);
                    }
                    const int col  = l & 15;
                    const int rowg = l >> 4;
                    if (col < TI && rowg < 2) {
                        #pragma unroll
                        for (int q = 0; q < 4; ++q)
                            Cst[il][rowg * 4 + q][col] = acc4[q];
                    }
                }
                __syncthreads();
                // coalesced RMW: t -> (s_local = t>>6, b = (t>>3)&7, i = t&7)
                {
                    const int ii  = t & 7;
                    const int b   = (t >> 3) & 7;
                    const int sl2 = t >> 6;
                    const int s   = sb + sl2;
                    out[(b * SD + s) * OD + i0 + ii] += Cst[sl2][b][ii];
                }
                __syncthreads();   // protect Wl/Xl/Cst for next super-step
            }
        }
    }
}

extern "C" void kernel_launch(void* const* d_in, const int* in_sizes, int n_in,
                              void* d_out, int out_size, void* d_ws, size_t ws_size,
                              hipStream_t stream) {
    const float* seq   = (const float*)d_in[0];
    const float* M     = (const float*)d_in[1];
    const float* P     = (const float*)d_in[2];
    const float* resW  = (const float*)d_in[3];
    const float* gamma = (const float*)d_in[4];
    const float* beta  = (const float*)d_in[5];
    float* out = (float*)d_out;

    ushort* xnT = (ushort*)d_ws;                        // 2 MB bf16 [s][b][j]
    float*  P4  = (float*)(xnT + SD * BD * OD);         // 384 KB
    float*  MT  = P4 + OD * OD * NBD;                   // 32 KB
    float*  RT  = MT + OD * ID;                         // 32 KB

    void* args[] = { (void*)&seq, (void*)&M, (void*)&P, (void*)&resW,
                     (void*)&gamma, (void*)&beta,
                     (void*)&P4, (void*)&MT, (void*)&RT, (void*)&xnT, (void*)&out };
    hipLaunchCooperativeKernel((void*)fused_all, dim3(256), dim3(512),
                               args, 0, stream);
}

// Round 14
// 37.163 us; speedup vs baseline: 5.2860x; 5.2860x over previous
//
#include <hip/hip_runtime.h>
#include <math.h>

#define BD 8
#define SD 1024
#define ID 64
#define OD 128
#define NBD 6
#define TI 4            // i-tile per nk block
#define SCH 32          // s-chunk per block (Chebyshev re-init interval)
#define SS 8            // s per super-step (one MFMA wave each)
#define WPAD 136        // padded LDS row (bf16 elems): 272B stride, 4-bank skew

typedef short bf16x8 __attribute__((ext_vector_type(8)));
typedef float f32x4 __attribute__((ext_vector_type(4)));

__device__ __forceinline__ ushort rne_bf16(float f) {
    union { float f; unsigned u; } cv; cv.f = f;
    return (ushort)((cv.u + 0x7FFFu + ((cv.u >> 16) & 1u)) >> 16);
}

// ---- prep: MT/RT transposed weights only (P read raw by nk) ----------------
__global__ __launch_bounds__(256) void prep_kernel(
    const float* __restrict__ M, const float* __restrict__ resW,
    float* __restrict__ MT, float* __restrict__ RT)
{
    const int idx = blockIdx.x * 256 + threadIdx.x;
    if (idx < OD * ID) {
        const int i = idx / ID, j = idx - i * ID;
        MT[j * OD + i] = M[idx];
    } else if (idx < 2 * OD * ID) {
        const int k = idx - OD * ID;
        const int i = k / ID, j = k - i * ID;
        RT[j * OD + i] = resW[k];
    }
}

// ---- Kernel A: weight-stationary proj + LN -> xnT (bf16); residual -> out --
__global__ __launch_bounds__(256) void ln_kernel(
    const float* __restrict__ seq,    // (8,1024,64)
    const float* __restrict__ MT,     // (64,128) [j][i]
    const float* __restrict__ RT,     // (64,128) [j][i]
    const float* __restrict__ gamma,
    const float* __restrict__ beta,
    ushort* __restrict__ xnT,         // (1024,8,128) bf16 [s][b][j]
    float* __restrict__ out)          // (8,1024,128) gets residual
{
    const int t   = threadIdx.x;
    const int s   = blockIdx.x;
    const int i   = t & 127;
    const int mat = t >> 7;           // wave-uniform
    __shared__ float red[2][16];

    float w[ID];
    {
        const float* __restrict__ WT = (mat ? RT : MT) + i;
        #pragma unroll
        for (int j = 0; j < ID; ++j) w[j] = WT[j * OD];   // coalesced
    }
    const float gm = gamma[i];
    const float bt = beta[i];

    float acc[BD];
    #pragma unroll
    for (int b = 0; b < BD; ++b) {
        const float* __restrict__ xp = &seq[(b * SD + s) * ID];  // uniform -> s_load
        float a0 = 0.f, a1 = 0.f;
        #pragma unroll
        for (int j = 0; j < ID; j += 2) {
            a0 = fmaf(xp[j],     w[j],     a0);
            a1 = fmaf(xp[j + 1], w[j + 1], a1);
        }
        acc[b] = a0 + a1;
    }

    if (mat == 0) {
        float sum[BD], ssq[BD];
        #pragma unroll
        for (int b = 0; b < BD; ++b) { sum[b] = acc[b]; ssq[b] = acc[b] * acc[b]; }
        #pragma unroll
        for (int m = 1; m < 64; m <<= 1) {
            #pragma unroll
            for (int b = 0; b < BD; ++b) {
                sum[b] += __shfl_xor(sum[b], m, 64);
                ssq[b] += __shfl_xor(ssq[b], m, 64);
            }
        }
        if ((t & 63) == 0) {
            const int wv = t >> 6;
            #pragma unroll
            for (int b = 0; b < BD; ++b) {
                red[wv][b]     = sum[b];
                red[wv][8 + b] = ssq[b];
            }
        }
    }
    __syncthreads();

    if (mat == 0) {
        #pragma unroll
        for (int b = 0; b < BD; ++b) {
            const float sm = red[0][b] + red[1][b];
            const float sq = red[0][8 + b] + red[1][8 + b];
            const float mu = sm * (1.0f / OD);
            const float vr = sq * (1.0f / OD) - mu * mu;
            const float rstd = rsqrtf(vr + 1e-5f);
            const float xv = (acc[b] - mu) * rstd * gm + bt;
            xnT[(s * BD + b) * OD + i] = rne_bf16(xv);   // coalesced b16 stores
        }
    } else {
        #pragma unroll
        for (int b = 0; b < BD; ++b)
            out[(b * SD + s) * OD + i] = acc[b];
    }
}

// ---- Kernel B: fused Chebyshev W-gen + MFMA, out += Nk ---------------------
// grid (32 s-chunks, 32 i-tiles of 4), 512 threads.
// W-gen role: thread = (iw = t>>7 in 0..3, jb = t&127), 6 Chebyshev states.
// MFMA role:  wave wv = t>>6 handles s = sb + wv; lane l = t&63.
__global__ __launch_bounds__(512, 6) void nk_kernel(
    const float* __restrict__ P,      // (128,128,6) raw [i][j][g]
    const ushort* __restrict__ xnT,   // [s][b][j] bf16
    float* __restrict__ out)          // (8,1024,128)
{
    const int sc = blockIdx.x;        // s in [sc*SCH, (sc+1)*SCH)
    const int i0 = blockIdx.y * TI;
    const int t  = threadIdx.x;
    const int iw = t >> 7;            // 0..3 local i (W-gen role)
    const int jb = t & 127;
    const int wv = t >> 6;            // 0..7 wave id (MFMA role)
    const int l  = t & 63;

    __shared__ ushort Wl[SS][TI][WPAD];    // 8.7 KB
    __shared__ ushort Xl[SS][BD][WPAD];    // 17.4 KB
    __shared__ float  Cst[SS][BD][TI];     // 1 KB epilogue stage

    // ---- init 6 Chebyshev states for (i0+iw, jb) ----
    float Pv[NBD], kk[NBD], c0[NBD], c1[NBD];
    const int ig = i0 + iw;
    const float s0f = (float)(sc * SCH);
    #pragma unroll
    for (int g = 0; g < NBD; ++g) {
        Pv[g] = P[(ig * OD + jb) * NBD + g];               // L2-hot, once/block
        const float per = (float)(ig * (OD * NBD) + jb * NBD + g + 2); // exact int
        const float rp  = __builtin_amdgcn_rcpf(per);      // revolutions per step
        kk[g] = 2.0f * __builtin_amdgcn_cosf(rp);
        c1[g] = __builtin_amdgcn_cosf(__builtin_amdgcn_fractf(s0f * rp));
        c0[g] = __builtin_amdgcn_cosf(__builtin_amdgcn_fractf((s0f - 1.0f) * rp));
    }

    for (int u = 0; u < SCH / SS; ++u) {
        const int sb = sc * SCH + u * SS;
        // ---- stage xn tile: 8s x 8b x 128j bf16 = 16 KB (coalesced uint4) ----
        {
            const uint4* __restrict__ src = (const uint4*)(xnT + sb * (BD * OD));
            #pragma unroll
            for (int r = 0; r < 2; ++r) {
                const int e  = t + 512 * r;       // uint4 index (1024 total)
                const uint4 v = src[e];
                const int eo = e << 3;            // bf16 elem offset
                const int si = eo >> 10;
                const int b  = (eo >> 7) & 7;
                const int j0 = eo & 127;
                *(uint4*)&Xl[si][b][j0] = v;
            }
        }
        // ---- W-gen: 8 s x (i0+iw, jb), 2 FMA/element ----
        #pragma unroll
        for (int ssi = 0; ssi < SS; ++ssi) {
            float wvv = 0.f;
            #pragma unroll
            for (int g = 0; g < NBD; ++g) wvv = fmaf(Pv[g], c1[g], wvv);
            #pragma unroll
            for (int g = 0; g < NBD; ++g) {
                const float cn = fmaf(kk[g], c1[g], -c0[g]);   // Chebyshev step
                c0[g] = c1[g]; c1[g] = cn;
            }
            Wl[ssi][iw][jb] = rne_bf16(wvv);
        }
        __syncthreads();
        // ---- MFMA: wave wv handles s = sb + wv ----
        {
            f32x4 acc4 = {0.f, 0.f, 0.f, 0.f};
            #pragma unroll
            for (int m = 0; m < 4; ++m) {
                // A[row=b][k=j]: row = l&7 (rows 8..15 dup, discarded)
                const bf16x8 a = *(const bf16x8*)&Xl[wv][l & 7][m * 32 + (l >> 4) * 8];
                // B[k=j][col=i] = W[col][k]: col = l&3 (cols 4..15 dup, discarded)
                const bf16x8 b = *(const bf16x8*)&Wl[wv][l & 3][m * 32 + (l >> 4) * 8];
                acc4 = __builtin_amdgcn_mfma_f32_16x16x32_bf16(a, b, acc4, 0, 0, 0);
            }
            const int col  = l & 15;
            const int rowg = l >> 4;
            if (col < TI && rowg < 2) {
                #pragma unroll
                for (int q = 0; q < 4; ++q)
                    Cst[wv][rowg * 4 + q][col] = acc4[q];
            }
        }
        __syncthreads();
        // ---- coalesced RMW: 256 threads, t -> (s=t>>5, b=(t>>2)&7, i=t&3) ----
        if (t < SS * BD * TI) {
            const int ii  = t & 3;
            const int b   = (t >> 2) & 7;
            const int sl2 = t >> 5;
            out[(b * SD + sb + sl2) * OD + i0 + ii] += Cst[sl2][b][ii];
        }
        __syncthreads();   // protect Wl/Xl/Cst before next super-step
    }
}

extern "C" void kernel_launch(void* const* d_in, const int* in_sizes, int n_in,
                              void* d_out, int out_size, void* d_ws, size_t ws_size,
                              hipStream_t stream) {
    const float* seq   = (const float*)d_in[0];
    const float* M     = (const float*)d_in[1];
    const float* P     = (const float*)d_in[2];
    const float* resW  = (const float*)d_in[3];
    const float* gamma = (const float*)d_in[4];
    const float* beta  = (const float*)d_in[5];
    float* out = (float*)d_out;

    ushort* xnT = (ushort*)d_ws;                        // 2 MB bf16 [s][b][j]
    float*  MT  = (float*)(xnT + SD * BD * OD);         // 32 KB
    float*  RT  = MT + OD * ID;                         // 32 KB

    prep_kernel<<<dim3((2 * OD * ID) / 256), dim3(256), 0, stream>>>(M, resW, MT, RT);
    ln_kernel<<<dim3(SD), dim3(256), 0, stream>>>(seq, MT, RT, gamma, beta,
                                                  xnT, out);
    nk_kernel<<<dim3(SD / SCH, OD / TI), dim3(512), 0, stream>>>(P, xnT, out);
}